// Round 13
// baseline (174.557 us; speedup 1.0000x reference)
//
#include <hip/hip_runtime.h>
#include <hip/hip_bf16.h>
#include <math.h>

// ---------------------------------------------------------------------------
// Round 20: r13 VERBATIM (best: 114us) + VOP3P packed-f32 VALU compression.
// r19 post-mortem: register ledger = 256/wave budget - 128 AGPR weights -
// 124 producer arch = 4 regs headroom -> ALL producer-side ILP additions
// (r11 pairs, r19 pipeline) structurally infeasible. Only zero-register
// lever left: cut VALU instruction COUNT in place. gfx90a+ VOP3P:
// v_pk_fma_f32 / v_pk_add_f32 (full-rate 2xf32; no pk_max -> relu scalar);
// compiler never emits them from scalar code -> inline asm (VALU asm is
// safe; r14's failure was MFMA/AGPR hazard-specific).
//   1. Y1 build: 32 fma -> 16 pk_fma/tile (pairs feed pk_bf16(lo,hi))
//   2. L4: 32 fmaf -> 16 pk_fma over 4 accumulator pairs (also breaks the
//      32-deep serial chain)
//   3. hpart prologue: 63x16 fma -> 63x8 pk_fma (~-1000 cyc/block)
// Per-element math identical (fma); L4 split-sum reassociation ~1e-6.
// Decision rule: dur flat + VALUBusy down => VALU count off critical path
// => plateau is latency-structural; declare local-minimum ceiling.
// ---------------------------------------------------------------------------

#define B_N    16384
#define KQ     51
#define HD     128
#define IND    64
#define BLK    128               // 2 waves: producer + consumer
#define RPB    16                // b-rows per block
#define GRID   (B_N / RPB)       // 1024
#define TPB    ((RPB * KQ) / 16) // 51 tiles per block (exact)

typedef __attribute__((ext_vector_type(8))) short short8;
typedef __attribute__((ext_vector_type(4))) float f32x4;
typedef __attribute__((ext_vector_type(2))) float f32x2;

union S8U { short8 s8; unsigned u[4]; };

__device__ __forceinline__ unsigned short f2bf(float f) {
    __hip_bfloat16 t = __float2bfloat16(f);
    return *reinterpret_cast<unsigned short*>(&t);
}

#if defined(__gfx950__) && defined(__has_builtin)
#if __has_builtin(__builtin_amdgcn_cvt_pk_bf16_f32)
#define HAVE_PK_BF16 1
#endif
#endif

__device__ __forceinline__ unsigned pk_bf16(float lo, float hi) {
#ifdef HAVE_PK_BF16
    typedef __attribute__((ext_vector_type(2))) __bf16 bfv2;
    bfv2 r = __builtin_amdgcn_cvt_pk_bf16_f32(lo, hi);
    return *reinterpret_cast<unsigned*>(&r);
#else
    return (unsigned)f2bf(lo) | ((unsigned)f2bf(hi) << 16);
#endif
}

// packed 2xf32 fma: d = a*b + c per 32-bit half (VOP3P, full rate gfx90a+)
__device__ __forceinline__ f32x2 pk_fma(f32x2 a, f32x2 b, f32x2 c) {
    f32x2 d;
    asm("v_pk_fma_f32 %0, %1, %2, %3" : "=v"(d) : "v"(a), "v"(b), "v"(c));
    return d;
}

__launch_bounds__(BLK, 2)
__global__ void umnn_fused(const float* __restrict__ x,  const float* __restrict__ h,
                           const float* __restrict__ W1, const float* __restrict__ b1,
                           const float* __restrict__ W2, const float* __restrict__ b2,
                           const float* __restrict__ W3, const float* __restrict__ b3,
                           const float* __restrict__ W4, const float* __restrict__ b4,
                           float* __restrict__ out)
{
    __shared__ __align__(16) float hpL[RPB * HD];      // 8 KB block hpart
    __shared__ __align__(16) char  y2x[2][4096];       // 8 KB Y2 double buffer
    __shared__ __align__(16) float hshT[63 * 20];      // 5 KB h^T staging
    __shared__ __align__(16) float vs4[TPB * 64];      // 12.75 KB per-lane partials
    __shared__ __align__(16) float b2f[HD], b3f[HD];   // 1 KB fp32 bias tables
    __shared__ float xL[RPB];
    __shared__ float sSteps[KQ], sCcw[KQ];
    __shared__ float red2[2];

    const int tid  = threadIdx.x;
    const int w    = tid >> 6;
    const int lane = tid & 63;
    const int q    = lane >> 4;
    const int lm   = lane & 15;
    const int swz  = lm & 7;
    const int rowBase = blockIdx.x * RPB;

    // ---- CC tables (validated r4 formula) ----
    if (tid < KQ) {
        const int j = tid;
        const float pi50 = 0.06283185307179586f;
        sSteps[j] = __cosf((float)j * pi50);
        float s = 0.0f;
        for (int i = 0; i <= 50; i += 2) {
            float Wi = (i == 0) ? 1.0f : 2.0f / (1.0f - (float)(i * i));
            float lam;
            if (j == 0) lam = 0.5f;
            else {
                int mp = (i * j) % 100;
                lam = __cosf((float)mp * pi50);
                if (j == 50) lam *= 0.5f;
            }
            s += (lam * 0.04f) * Wi;
        }
        sCcw[j] = s;
    }
    // ---- fp32 bias tables ----
    if (tid < HD) {
        b2f[tid] = b2[tid];
        b3f[tid] = b3[tid];
    }
    // ---- xmax scan (x: 64 KB, cache-resident) ----
    {
        const f32x4* x4 = (const f32x4*)x;
        float mx = -1e30f;
        for (int i = tid; i < B_N / 4; i += BLK) {
            f32x4 v = x4[i];
            mx = fmaxf(fmaxf(mx, fmaxf(v[0], v[1])), fmaxf(v[2], v[3]));
        }
        #pragma unroll
        for (int d = 32; d > 0; d >>= 1) mx = fmaxf(mx, __shfl_xor(mx, d));
        if (lane == 0) red2[w] = mx;
    }
    // ---- stage h^T for this block's 16 rows; init xL ----
    for (int i = tid; i < RPB * 63; i += BLK) {
        int r = i / 63, d = i - r * 63;
        hshT[d * 20 + r] = h[rowBase * 63 + i];
    }
    if (tid < RPB) xL[tid] = x[rowBase + tid];
    __syncthreads();                                   // B1

    const float xmax = fmaxf(red2[0], red2[1]) + 10.0f;

    // ---- block hpart: thread tid = feature n, 8 pk-paired row accums ----
    {
        const int n = tid;
        f32x2 acc2[RPB / 2];
        const float b1v = b1[n];
        #pragma unroll
        for (int r = 0; r < RPB / 2; ++r) acc2[r] = (f32x2){b1v, b1v};
        const float* wr = W1 + n * IND + 1;
        #pragma unroll 1
        for (int d = 0; d < IND - 1; ++d) {
            const float wv = wr[d];
            const f32x2 wv2 = {wv, wv};
            const float* ht = hshT + d * 20;
            #pragma unroll
            for (int rc = 0; rc < RPB / 4; ++rc) {
                f32x4 hv = *(const f32x4*)(ht + rc * 4);
                acc2[rc * 2 + 0] = pk_fma(wv2, (f32x2){hv[0], hv[1]}, acc2[rc * 2 + 0]);
                acc2[rc * 2 + 1] = pk_fma(wv2, (f32x2){hv[2], hv[3]}, acc2[rc * 2 + 1]);
            }
        }
        #pragma unroll
        for (int r = 0; r < RPB; ++r) hpL[r * HD + n] = acc2[r >> 1][r & 1];
    }
    __syncthreads();                                   // B2 (hpL ready)

    // per-lane C-init byte offset into bias table: feature nt*16+q*4
    const int bIoff = q * 16;                          // + nt*64 at use site

    if (w == 0) {
        // ================= PRODUCER: layer 1 + layer 2 =================
        __builtin_amdgcn_s_setprio(0);
        // W1 x-column as pk pairs: w1p[kk*4+j] = {w1x[kk*8+2j], w1x[kk*8+2j+1]}
        f32x2 w1p[16];
        #pragma unroll
        for (int kk = 0; kk < 4; ++kk)
            #pragma unroll
            for (int j = 0; j < 4; ++j)
                w1p[kk * 4 + j] = (f32x2){W1[(kk * 32 + q * 8 + 2 * j) * IND],
                                          W1[(kk * 32 + q * 8 + 2 * j + 1) * IND]};

        short8 W2A[8][4];
        #pragma unroll
        for (int nt = 0; nt < 8; ++nt) {
            #pragma unroll
            for (int kk = 0; kk < 4; ++kk) {
                const float* p2 = W2 + (nt * 16 + lm) * HD + kk * 32 + q * 8;
                S8U a2;
                #pragma unroll
                for (int j = 0; j < 4; ++j)
                    a2.u[j] = pk_bf16(p2[2 * j], p2[2 * j + 1]);
                W2A[nt][kk] = a2.s8;
            }
        }
        int wrOff[8];
        #pragma unroll
        for (int nt = 0; nt < 8; ++nt)
            wrOff[nt] = lm * 256 + (((2 * nt + (q >> 1)) ^ swz) << 4) + ((q & 1) << 3);
        const char* b2c = (const char*)b2f;

        #pragma unroll 1
        for (int tt = 0; tt < TPB; ++tt) {
            // ---- layer 1: build Y1 fragment (pk_fma pairs) ----
            const int s    = tt * 16 + lm;             // 0..815
            const unsigned row = (unsigned)s / KQ;     // 0..15
            const int k    = s - (int)row * KQ;
            const float x0 = xL[row];
            const float X  = fmaf((xmax - x0) * 0.5f, sSteps[k] + 1.0f, x0);
            const f32x2 X2 = {X, X};
            short8 Y1[4];
            #pragma unroll
            for (int kk = 0; kk < 4; ++kk) {
                const float* hp = hpL + row * HD + kk * 32 + q * 8;
                f32x4 ha = *(const f32x4*)hp;
                f32x4 hb = *(const f32x4*)(hp + 4);
                f32x2 t0 = pk_fma(X2, w1p[kk * 4 + 0], (f32x2){ha[0], ha[1]});
                f32x2 t1 = pk_fma(X2, w1p[kk * 4 + 1], (f32x2){ha[2], ha[3]});
                f32x2 t2 = pk_fma(X2, w1p[kk * 4 + 2], (f32x2){hb[0], hb[1]});
                f32x2 t3 = pk_fma(X2, w1p[kk * 4 + 3], (f32x2){hb[2], hb[3]});
                S8U u;
                u.u[0] = pk_bf16(fmaxf(t0[0], 0.f), fmaxf(t0[1], 0.f));
                u.u[1] = pk_bf16(fmaxf(t1[0], 0.f), fmaxf(t1[1], 0.f));
                u.u[2] = pk_bf16(fmaxf(t2[0], 0.f), fmaxf(t2[1], 0.f));
                u.u[3] = pk_bf16(fmaxf(t3[0], 0.f), fmaxf(t3[1], 0.f));
                Y1[kk] = u.s8;
            }

            // ---- layer 2: C init from LDS bias table, 32 MFMA ----
            f32x4 C[8];
            #pragma unroll
            for (int nt = 0; nt < 8; ++nt)
                C[nt] = *(const f32x4*)(b2c + nt * 64 + bIoff);
            #pragma unroll
            for (int kk = 0; kk < 4; ++kk)
                #pragma unroll
                for (int nt = 0; nt < 8; ++nt)
                    C[nt] = __builtin_amdgcn_mfma_f32_16x16x32_bf16(W2A[nt][kk], Y1[kk], C[nt], 0, 0, 0);

            // ---- relu + pack + write Y2 ----
            char* d2 = y2x[tt & 1];
            #pragma unroll
            for (int nt = 0; nt < 8; ++nt) {
                unsigned lo = pk_bf16(fmaxf(C[nt][0], 0.f), fmaxf(C[nt][1], 0.f));
                unsigned hi = pk_bf16(fmaxf(C[nt][2], 0.f), fmaxf(C[nt][3], 0.f));
                *(int2*)(d2 + wrOff[nt]) = make_int2((int)lo, (int)hi);
            }
            __syncthreads();                           // tile tt ready
        }
    } else {
        // ================= CONSUMER: layer 3 + layer 4 =================
        __builtin_amdgcn_s_setprio(1);                 // consumer is critical
        short8 W3A[8][4];
        f32x2  W4p[16];                                // W4 as pk pairs
        #pragma unroll
        for (int nt = 0; nt < 8; ++nt) {
            #pragma unroll
            for (int kk = 0; kk < 4; ++kk) {
                const float* p3 = W3 + (nt * 16 + lm) * HD + kk * 32 + q * 8;
                S8U a3;
                #pragma unroll
                for (int j = 0; j < 4; ++j)
                    a3.u[j] = pk_bf16(p3[2 * j], p3[2 * j + 1]);
                W3A[nt][kk] = a3.s8;
            }
            const float* w4 = W4 + nt * 16 + q * 4;
            W4p[2 * nt + 0] = (f32x2){w4[0], w4[1]};
            W4p[2 * nt + 1] = (f32x2){w4[2], w4[3]};
        }
        const float b4v = b4[0];
        int rdOff[4];
        #pragma unroll
        for (int kk = 0; kk < 4; ++kk)
            rdOff[kk] = lm * 256 + (((kk * 4 + q) ^ swz) << 4);
        const char* b3c = (const char*)b3f;

        #pragma unroll 1
        for (int tt = 0; tt < TPB; ++tt) {
            __syncthreads();                           // wait for tile tt
            const char* s2 = y2x[tt & 1];

            // chain head: Y2 reads + C-init reads, all pipelined LDS
            short8 Y2[4];
            #pragma unroll
            for (int kk = 0; kk < 4; ++kk)
                Y2[kk] = *(const short8*)(s2 + rdOff[kk]);
            f32x4 C[8];
            #pragma unroll
            for (int nt = 0; nt < 8; ++nt)
                C[nt] = *(const f32x4*)(b3c + nt * 64 + bIoff);

            #pragma unroll
            for (int kk = 0; kk < 4; ++kk)
                #pragma unroll
                for (int nt = 0; nt < 8; ++nt)
                    C[nt] = __builtin_amdgcn_mfma_f32_16x16x32_bf16(W3A[nt][kk], Y2[kk], C[nt], 0, 0, 0);

            // ---- layer 4: relu + pk_fma over 4 accumulator pairs ----
            f32x2 a0 = {0.f, 0.f}, a1 = {0.f, 0.f};
            f32x2 a2 = {0.f, 0.f}, a3 = {0.f, 0.f};
            #pragma unroll
            for (int nt = 0; nt < 8; ++nt) {
                f32x2 r0 = {fmaxf(C[nt][0], 0.f), fmaxf(C[nt][1], 0.f)};
                f32x2 r1 = {fmaxf(C[nt][2], 0.f), fmaxf(C[nt][3], 0.f)};
                if (nt & 1) {
                    a2 = pk_fma(r0, W4p[2 * nt + 0], a2);
                    a3 = pk_fma(r1, W4p[2 * nt + 1], a3);
                } else {
                    a0 = pk_fma(r0, W4p[2 * nt + 0], a0);
                    a1 = pk_fma(r1, W4p[2 * nt + 1], a1);
                }
            }
            vs4[tt * 64 + lane] = ((a0[0] + a0[1]) + (a1[0] + a1[1]))
                                + ((a2[0] + a2[1]) + (a3[0] + a3[1]));
        }

        // ---- deferred epilogue: 4-way quarter sum + elu + ccw + reduce ----
        {
            const int r   = lane >> 2;                 // row 0..15
            const int sub = lane & 3;
            float a = 0.f;
            #pragma unroll 1
            for (int j = 0; j < 13; ++j) {
                int k = sub + 4 * j;
                if (k < KQ) {
                    int s   = r * KQ + k;
                    int tt  = s >> 4;
                    int lm2 = s & 15;
                    const float* vb = vs4 + tt * 64 + lm2;
                    float y4 = vb[0] + vb[16] + vb[32] + vb[48] + b4v;
                    float f  = (y4 > 0.f) ? (y4 + 1.f) : __expf(y4);
                    a = fmaf(f, sCcw[k], a);
                }
            }
            a += __shfl_xor(a, 1);
            a += __shfl_xor(a, 2);
            if (sub == 0)
                out[rowBase + r] = a * (xmax - xL[r]) * 0.5f;
        }
    }
}

// ---------------------------------------------------------------------------
extern "C" void kernel_launch(void* const* d_in, const int* in_sizes, int n_in,
                              void* d_out, int out_size, void* d_ws, size_t ws_size,
                              hipStream_t stream)
{
    const float* x  = (const float*)d_in[0];
    const float* h  = (const float*)d_in[1];
    const float* W1 = (const float*)d_in[2];
    const float* b1 = (const float*)d_in[3];
    const float* W2 = (const float*)d_in[4];
    const float* b2 = (const float*)d_in[5];
    const float* W3 = (const float*)d_in[6];
    const float* b3 = (const float*)d_in[7];
    const float* W4 = (const float*)d_in[8];
    const float* b4 = (const float*)d_in[9];
    float* out = (float*)d_out;

    umnn_fused<<<GRID, BLK, 0, stream>>>(x, h, W1, b1, W2, b2, W3, b3,
                                         W4, b4, out);
}

// Round 14
// 169.703 us; speedup vs baseline: 1.0286x; 1.0286x over previous
//
#include <hip/hip_runtime.h>
#include <hip/hip_bf16.h>
#include <math.h>

// ---------------------------------------------------------------------------
// Round 21 (FINAL): exact revert to r13 -- the session's measured best
// (rocprof 113.7-117.9us band; every later variant 118-157us or failed).
// Architecture: 2-wave producer/consumer, per-tile barrier, bf16 Y2 handoff.
//   producer (wave 0): Y1 build on VALU (fp32 hpart + X-col fma/relu/pack),
//     32 MFMA layer-2, relu+pack+swizzled Y2 write. ~124 arch regs + 128
//     AGPR (W2) -- 4 regs of headroom, occupancy locked at 2 waves/SIMD.
//   consumer (wave 1): swizzled Y2 read, 32 MFMA layer-3, per-lane L4
//     partial straight to LDS (no shuffles), deferred elu/ccw epilogue.
// Measured dead ends (do not revisit): sync topology (pair-barriers 119,
// flag-ring 125), 4-wave split-weights (144/spill/numerics), L1-on-MFMA
// (122, longer producer span), consumer span cuts (120), pk_fma (118,
// mov overhead), asm-pinned AGPR MFMA (hazard corruption). Limit is
// latency at register-forced 2 waves/SIMD: 128-AGPR weight residency is
// irreducible (LDS streaming > LDS BW; fp8 weights > error budget).
// Numerics: absmax 0.125 vs threshold 0.4725.
// ---------------------------------------------------------------------------

#define B_N    16384
#define KQ     51
#define HD     128
#define IND    64
#define BLK    128               // 2 waves: producer + consumer
#define RPB    16                // b-rows per block
#define GRID   (B_N / RPB)       // 1024
#define TPB    ((RPB * KQ) / 16) // 51 tiles per block (exact)

typedef __attribute__((ext_vector_type(8))) short short8;
typedef __attribute__((ext_vector_type(4))) float f32x4;

union S8U { short8 s8; unsigned u[4]; };

__device__ __forceinline__ unsigned short f2bf(float f) {
    __hip_bfloat16 t = __float2bfloat16(f);
    return *reinterpret_cast<unsigned short*>(&t);
}

#if defined(__gfx950__) && defined(__has_builtin)
#if __has_builtin(__builtin_amdgcn_cvt_pk_bf16_f32)
#define HAVE_PK_BF16 1
#endif
#endif

__device__ __forceinline__ unsigned pk_bf16(float lo, float hi) {
#ifdef HAVE_PK_BF16
    typedef __attribute__((ext_vector_type(2))) __bf16 bfv2;
    bfv2 r = __builtin_amdgcn_cvt_pk_bf16_f32(lo, hi);
    return *reinterpret_cast<unsigned*>(&r);
#else
    return (unsigned)f2bf(lo) | ((unsigned)f2bf(hi) << 16);
#endif
}

__launch_bounds__(BLK, 2)
__global__ void umnn_fused(const float* __restrict__ x,  const float* __restrict__ h,
                           const float* __restrict__ W1, const float* __restrict__ b1,
                           const float* __restrict__ W2, const float* __restrict__ b2,
                           const float* __restrict__ W3, const float* __restrict__ b3,
                           const float* __restrict__ W4, const float* __restrict__ b4,
                           float* __restrict__ out)
{
    __shared__ __align__(16) float hpL[RPB * HD];      // 8 KB block hpart
    __shared__ __align__(16) char  y2x[2][4096];       // 8 KB Y2 double buffer
    __shared__ __align__(16) float hshT[63 * 20];      // 5 KB h^T staging
    __shared__ __align__(16) float vs4[TPB * 64];      // 12.75 KB per-lane partials
    __shared__ __align__(16) float b2f[HD], b3f[HD];   // 1 KB fp32 bias tables
    __shared__ float xL[RPB];
    __shared__ float sSteps[KQ], sCcw[KQ];
    __shared__ float red2[2];

    const int tid  = threadIdx.x;
    const int w    = tid >> 6;
    const int lane = tid & 63;
    const int q    = lane >> 4;
    const int lm   = lane & 15;
    const int swz  = lm & 7;
    const int rowBase = blockIdx.x * RPB;

    // ---- CC tables (validated r4 formula) ----
    if (tid < KQ) {
        const int j = tid;
        const float pi50 = 0.06283185307179586f;
        sSteps[j] = __cosf((float)j * pi50);
        float s = 0.0f;
        for (int i = 0; i <= 50; i += 2) {
            float Wi = (i == 0) ? 1.0f : 2.0f / (1.0f - (float)(i * i));
            float lam;
            if (j == 0) lam = 0.5f;
            else {
                int mp = (i * j) % 100;
                lam = __cosf((float)mp * pi50);
                if (j == 50) lam *= 0.5f;
            }
            s += (lam * 0.04f) * Wi;
        }
        sCcw[j] = s;
    }
    // ---- fp32 bias tables ----
    if (tid < HD) {
        b2f[tid] = b2[tid];
        b3f[tid] = b3[tid];
    }
    // ---- xmax scan (x: 64 KB, cache-resident) ----
    {
        const f32x4* x4 = (const f32x4*)x;
        float mx = -1e30f;
        for (int i = tid; i < B_N / 4; i += BLK) {
            f32x4 v = x4[i];
            mx = fmaxf(fmaxf(mx, fmaxf(v[0], v[1])), fmaxf(v[2], v[3]));
        }
        #pragma unroll
        for (int d = 32; d > 0; d >>= 1) mx = fmaxf(mx, __shfl_xor(mx, d));
        if (lane == 0) red2[w] = mx;
    }
    // ---- stage h^T for this block's 16 rows; init xL ----
    for (int i = tid; i < RPB * 63; i += BLK) {
        int r = i / 63, d = i - r * 63;
        hshT[d * 20 + r] = h[rowBase * 63 + i];
    }
    if (tid < RPB) xL[tid] = x[rowBase + tid];
    __syncthreads();                                   // B1

    const float xmax = fmaxf(red2[0], red2[1]) + 10.0f;

    // ---- block hpart: thread tid = feature n, 16 row-accumulators ----
    {
        const int n = tid;
        float acc[RPB];
        const float b1v = b1[n];
        #pragma unroll
        for (int r = 0; r < RPB; ++r) acc[r] = b1v;
        const float* wr = W1 + n * IND + 1;
        #pragma unroll 1
        for (int d = 0; d < IND - 1; ++d) {
            float wv = wr[d];
            const float* ht = hshT + d * 20;
            #pragma unroll
            for (int rc = 0; rc < RPB / 4; ++rc) {
                f32x4 hv = *(const f32x4*)(ht + rc * 4);
                acc[rc * 4 + 0] = fmaf(wv, hv[0], acc[rc * 4 + 0]);
                acc[rc * 4 + 1] = fmaf(wv, hv[1], acc[rc * 4 + 1]);
                acc[rc * 4 + 2] = fmaf(wv, hv[2], acc[rc * 4 + 2]);
                acc[rc * 4 + 3] = fmaf(wv, hv[3], acc[rc * 4 + 3]);
            }
        }
        #pragma unroll
        for (int r = 0; r < RPB; ++r) hpL[r * HD + n] = acc[r];
    }
    __syncthreads();                                   // B2 (hpL ready)

    // per-lane C-init byte offset into bias table: feature nt*16+q*4
    const int bIoff = q * 16;                          // + nt*64 at use site

    if (w == 0) {
        // ================= PRODUCER: layer 1 + layer 2 =================
        __builtin_amdgcn_s_setprio(0);
        float w1x[32];
        #pragma unroll
        for (int kk = 0; kk < 4; ++kk)
            #pragma unroll
            for (int j = 0; j < 8; ++j)
                w1x[kk * 8 + j] = W1[(kk * 32 + q * 8 + j) * IND];

        short8 W2A[8][4];
        #pragma unroll
        for (int nt = 0; nt < 8; ++nt) {
            #pragma unroll
            for (int kk = 0; kk < 4; ++kk) {
                const float* p2 = W2 + (nt * 16 + lm) * HD + kk * 32 + q * 8;
                S8U a2;
                #pragma unroll
                for (int j = 0; j < 4; ++j)
                    a2.u[j] = pk_bf16(p2[2 * j], p2[2 * j + 1]);
                W2A[nt][kk] = a2.s8;
            }
        }
        int wrOff[8];
        #pragma unroll
        for (int nt = 0; nt < 8; ++nt)
            wrOff[nt] = lm * 256 + (((2 * nt + (q >> 1)) ^ swz) << 4) + ((q & 1) << 3);
        const char* b2c = (const char*)b2f;

        #pragma unroll 1
        for (int tt = 0; tt < TPB; ++tt) {
            // ---- layer 1: build Y1 fragment for this tile ----
            const int s    = tt * 16 + lm;             // 0..815
            const unsigned row = (unsigned)s / KQ;     // 0..15
            const int k    = s - (int)row * KQ;
            const float x0 = xL[row];
            const float X  = fmaf((xmax - x0) * 0.5f, sSteps[k] + 1.0f, x0);
            short8 Y1[4];
            #pragma unroll
            for (int kk = 0; kk < 4; ++kk) {
                const float* hp = hpL + row * HD + kk * 32 + q * 8;
                f32x4 ha = *(const f32x4*)hp;
                f32x4 hb = *(const f32x4*)(hp + 4);
                S8U u;
                u.u[0] = pk_bf16(fmaxf(fmaf(X, w1x[kk*8+0], ha[0]), 0.f),
                                 fmaxf(fmaf(X, w1x[kk*8+1], ha[1]), 0.f));
                u.u[1] = pk_bf16(fmaxf(fmaf(X, w1x[kk*8+2], ha[2]), 0.f),
                                 fmaxf(fmaf(X, w1x[kk*8+3], ha[3]), 0.f));
                u.u[2] = pk_bf16(fmaxf(fmaf(X, w1x[kk*8+4], hb[0]), 0.f),
                                 fmaxf(fmaf(X, w1x[kk*8+5], hb[1]), 0.f));
                u.u[3] = pk_bf16(fmaxf(fmaf(X, w1x[kk*8+6], hb[2]), 0.f),
                                 fmaxf(fmaf(X, w1x[kk*8+7], hb[3]), 0.f));
                Y1[kk] = u.s8;
            }

            // ---- layer 2: C init from LDS bias table, 32 MFMA ----
            f32x4 C[8];
            #pragma unroll
            for (int nt = 0; nt < 8; ++nt)
                C[nt] = *(const f32x4*)(b2c + nt * 64 + bIoff);
            #pragma unroll
            for (int kk = 0; kk < 4; ++kk)
                #pragma unroll
                for (int nt = 0; nt < 8; ++nt)
                    C[nt] = __builtin_amdgcn_mfma_f32_16x16x32_bf16(W2A[nt][kk], Y1[kk], C[nt], 0, 0, 0);

            // ---- relu + pack + write Y2 ----
            char* d2 = y2x[tt & 1];
            #pragma unroll
            for (int nt = 0; nt < 8; ++nt) {
                unsigned lo = pk_bf16(fmaxf(C[nt][0], 0.f), fmaxf(C[nt][1], 0.f));
                unsigned hi = pk_bf16(fmaxf(C[nt][2], 0.f), fmaxf(C[nt][3], 0.f));
                *(int2*)(d2 + wrOff[nt]) = make_int2((int)lo, (int)hi);
            }
            __syncthreads();                           // tile tt ready
        }
    } else {
        // ================= CONSUMER: layer 3 + layer 4 =================
        __builtin_amdgcn_s_setprio(1);                 // consumer is critical
        short8 W3A[8][4];
        f32x4  W4c[8];
        #pragma unroll
        for (int nt = 0; nt < 8; ++nt) {
            #pragma unroll
            for (int kk = 0; kk < 4; ++kk) {
                const float* p3 = W3 + (nt * 16 + lm) * HD + kk * 32 + q * 8;
                S8U a3;
                #pragma unroll
                for (int j = 0; j < 4; ++j)
                    a3.u[j] = pk_bf16(p3[2 * j], p3[2 * j + 1]);
                W3A[nt][kk] = a3.s8;
            }
            W4c[nt] = *(const f32x4*)(W4 + nt * 16 + q * 4);
        }
        const float b4v = b4[0];
        int rdOff[4];
        #pragma unroll
        for (int kk = 0; kk < 4; ++kk)
            rdOff[kk] = lm * 256 + (((kk * 4 + q) ^ swz) << 4);
        const char* b3c = (const char*)b3f;

        #pragma unroll 1
        for (int tt = 0; tt < TPB; ++tt) {
            __syncthreads();                           // wait for tile tt
            const char* s2 = y2x[tt & 1];

            // chain head: Y2 reads + C-init reads, all pipelined LDS
            short8 Y2[4];
            #pragma unroll
            for (int kk = 0; kk < 4; ++kk)
                Y2[kk] = *(const short8*)(s2 + rdOff[kk]);
            f32x4 C[8];
            #pragma unroll
            for (int nt = 0; nt < 8; ++nt)
                C[nt] = *(const f32x4*)(b3c + nt * 64 + bIoff);

            #pragma unroll
            for (int kk = 0; kk < 4; ++kk)
                #pragma unroll
                for (int nt = 0; nt < 8; ++nt)
                    C[nt] = __builtin_amdgcn_mfma_f32_16x16x32_bf16(W3A[nt][kk], Y2[kk], C[nt], 0, 0, 0);

            // ---- layer 4 per-lane partial: NO shuffles, straight to LDS ----
            float p = 0.f;
            #pragma unroll
            for (int nt = 0; nt < 8; ++nt) {
                p = fmaf(fmaxf(C[nt][0], 0.f), W4c[nt][0], p);
                p = fmaf(fmaxf(C[nt][1], 0.f), W4c[nt][1], p);
                p = fmaf(fmaxf(C[nt][2], 0.f), W4c[nt][2], p);
                p = fmaf(fmaxf(C[nt][3], 0.f), W4c[nt][3], p);
            }
            vs4[tt * 64 + lane] = p;                   // conflict-free
        }

        // ---- deferred epilogue: 4-way quarter sum + elu + ccw + reduce ----
        {
            const int r   = lane >> 2;                 // row 0..15
            const int sub = lane & 3;
            float a = 0.f;
            #pragma unroll 1
            for (int j = 0; j < 13; ++j) {
                int k = sub + 4 * j;
                if (k < KQ) {
                    int s   = r * KQ + k;
                    int tt  = s >> 4;
                    int lm2 = s & 15;
                    const float* vb = vs4 + tt * 64 + lm2;
                    float y4 = vb[0] + vb[16] + vb[32] + vb[48] + b4v;
                    float f  = (y4 > 0.f) ? (y4 + 1.f) : __expf(y4);
                    a = fmaf(f, sCcw[k], a);
                }
            }
            a += __shfl_xor(a, 1);
            a += __shfl_xor(a, 2);
            if (sub == 0)
                out[rowBase + r] = a * (xmax - xL[r]) * 0.5f;
        }
    }
}

// ---------------------------------------------------------------------------
extern "C" void kernel_launch(void* const* d_in, const int* in_sizes, int n_in,
                              void* d_out, int out_size, void* d_ws, size_t ws_size,
                              hipStream_t stream)
{
    const float* x  = (const float*)d_in[0];
    const float* h  = (const float*)d_in[1];
    const float* W1 = (const float*)d_in[2];
    const float* b1 = (const float*)d_in[3];
    const float* W2 = (const float*)d_in[4];
    const float* b2 = (const float*)d_in[5];
    const float* W3 = (const float*)d_in[6];
    const float* b3 = (const float*)d_in[7];
    const float* W4 = (const float*)d_in[8];
    const float* b4 = (const float*)d_in[9];
    float* out = (float*)d_out;

    umnn_fused<<<GRID, BLK, 0, stream>>>(x, h, W1, b1, W2, b2, W3, b3,
                                         W4, b4, out);
}

// Round 15
// 162.309 us; speedup vs baseline: 1.0755x; 1.0456x over previous
//
#include <hip/hip_runtime.h>
#include <hip/hip_bf16.h>
#include <math.h>

// ---------------------------------------------------------------------------
// Round 22: r13/r21 structure (measured best) + PROLOGUE LOAD-PATH cleanup.
// Loop body byte-identical to r21. Two staging fixes, both bit-identical:
//   1. hpart W1 loads: was 63 dependent scalar global loads (#unroll 1,
//      ~6-8K serial cyc/block); now 16 aligned f32x4 chunk loads with
//      1-chunk software prefetch (row is contiguous, 16B-aligned from
//      row start; col 0 skipped in chunk 0). Accumulation order d=0..62
//      unchanged -> bit-identical hpart.
//   2. W2A/W3A staging: was 256 scalar 4B loads/wave; now 64 aligned
//      f32x4 loads feeding the same pk_bf16 chain -> bit-identical.
// Everything else verbatim r21 (2-wave P/C, per-tile barrier, bf16 Y2
// handoff, fp32 bias tables, vs4 no-shuffle L4, asym setprio).
// Measured dead ends (do not revisit): sync topology (119/125), 4-wave
// split-weights (144/spill/numerics), L1-on-MFMA (122), consumer span
// cuts (120), pk_fma (118), asm-pinned AGPR MFMA (corruption).
// Session noise floor: ~5 us across sessions (r13 re-measure drifted
// 114->121). Numerics: absmax 0.125 vs threshold 0.4725.
// ---------------------------------------------------------------------------

#define B_N    16384
#define KQ     51
#define HD     128
#define IND    64
#define BLK    128               // 2 waves: producer + consumer
#define RPB    16                // b-rows per block
#define GRID   (B_N / RPB)       // 1024
#define TPB    ((RPB * KQ) / 16) // 51 tiles per block (exact)

typedef __attribute__((ext_vector_type(8))) short short8;
typedef __attribute__((ext_vector_type(4))) float f32x4;

union S8U { short8 s8; unsigned u[4]; };

__device__ __forceinline__ unsigned short f2bf(float f) {
    __hip_bfloat16 t = __float2bfloat16(f);
    return *reinterpret_cast<unsigned short*>(&t);
}

#if defined(__gfx950__) && defined(__has_builtin)
#if __has_builtin(__builtin_amdgcn_cvt_pk_bf16_f32)
#define HAVE_PK_BF16 1
#endif
#endif

__device__ __forceinline__ unsigned pk_bf16(float lo, float hi) {
#ifdef HAVE_PK_BF16
    typedef __attribute__((ext_vector_type(2))) __bf16 bfv2;
    bfv2 r = __builtin_amdgcn_cvt_pk_bf16_f32(lo, hi);
    return *reinterpret_cast<unsigned*>(&r);
#else
    return (unsigned)f2bf(lo) | ((unsigned)f2bf(hi) << 16);
#endif
}

__launch_bounds__(BLK, 2)
__global__ void umnn_fused(const float* __restrict__ x,  const float* __restrict__ h,
                           const float* __restrict__ W1, const float* __restrict__ b1,
                           const float* __restrict__ W2, const float* __restrict__ b2,
                           const float* __restrict__ W3, const float* __restrict__ b3,
                           const float* __restrict__ W4, const float* __restrict__ b4,
                           float* __restrict__ out)
{
    __shared__ __align__(16) float hpL[RPB * HD];      // 8 KB block hpart
    __shared__ __align__(16) char  y2x[2][4096];       // 8 KB Y2 double buffer
    __shared__ __align__(16) float hshT[63 * 20];      // 5 KB h^T staging
    __shared__ __align__(16) float vs4[TPB * 64];      // 12.75 KB per-lane partials
    __shared__ __align__(16) float b2f[HD], b3f[HD];   // 1 KB fp32 bias tables
    __shared__ float xL[RPB];
    __shared__ float sSteps[KQ], sCcw[KQ];
    __shared__ float red2[2];

    const int tid  = threadIdx.x;
    const int w    = tid >> 6;
    const int lane = tid & 63;
    const int q    = lane >> 4;
    const int lm   = lane & 15;
    const int swz  = lm & 7;
    const int rowBase = blockIdx.x * RPB;

    // ---- CC tables (validated r4 formula) ----
    if (tid < KQ) {
        const int j = tid;
        const float pi50 = 0.06283185307179586f;
        sSteps[j] = __cosf((float)j * pi50);
        float s = 0.0f;
        for (int i = 0; i <= 50; i += 2) {
            float Wi = (i == 0) ? 1.0f : 2.0f / (1.0f - (float)(i * i));
            float lam;
            if (j == 0) lam = 0.5f;
            else {
                int mp = (i * j) % 100;
                lam = __cosf((float)mp * pi50);
                if (j == 50) lam *= 0.5f;
            }
            s += (lam * 0.04f) * Wi;
        }
        sCcw[j] = s;
    }
    // ---- fp32 bias tables ----
    if (tid < HD) {
        b2f[tid] = b2[tid];
        b3f[tid] = b3[tid];
    }
    // ---- xmax scan (x: 64 KB, cache-resident) ----
    {
        const f32x4* x4 = (const f32x4*)x;
        float mx = -1e30f;
        for (int i = tid; i < B_N / 4; i += BLK) {
            f32x4 v = x4[i];
            mx = fmaxf(fmaxf(mx, fmaxf(v[0], v[1])), fmaxf(v[2], v[3]));
        }
        #pragma unroll
        for (int d = 32; d > 0; d >>= 1) mx = fmaxf(mx, __shfl_xor(mx, d));
        if (lane == 0) red2[w] = mx;
    }
    // ---- stage h^T for this block's 16 rows; init xL ----
    for (int i = tid; i < RPB * 63; i += BLK) {
        int r = i / 63, d = i - r * 63;
        hshT[d * 20 + r] = h[rowBase * 63 + i];
    }
    if (tid < RPB) xL[tid] = x[rowBase + tid];
    __syncthreads();                                   // B1

    const float xmax = fmaxf(red2[0], red2[1]) + 10.0f;

    // ---- block hpart: thread tid = feature n, 16 row-accumulators.
    //      W1 row loaded as 16 aligned f32x4 chunks with 1-chunk prefetch
    //      (was 63 dependent scalar loads). Accum order d=0..62 unchanged.
    {
        const int n = tid;
        float acc[RPB];
        const float b1v = b1[n];
        #pragma unroll
        for (int r = 0; r < RPB; ++r) acc[r] = b1v;

        auto doFMA = [&](float wv, int d) {
            const float* ht = hshT + d * 20;
            #pragma unroll
            for (int rc = 0; rc < RPB / 4; ++rc) {
                f32x4 hv = *(const f32x4*)(ht + rc * 4);
                acc[rc * 4 + 0] = fmaf(wv, hv[0], acc[rc * 4 + 0]);
                acc[rc * 4 + 1] = fmaf(wv, hv[1], acc[rc * 4 + 1]);
                acc[rc * 4 + 2] = fmaf(wv, hv[2], acc[rc * 4 + 2]);
                acc[rc * 4 + 3] = fmaf(wv, hv[3], acc[rc * 4 + 3]);
            }
        };

        const float* w1row = W1 + n * IND;             // 16B-aligned row base
        f32x4 wc = *(const f32x4*)(w1row);             // cols 0..3 (col 0 = x-col, unused)
        f32x4 wn = *(const f32x4*)(w1row + 4);
        doFMA(wc[1], 0); doFMA(wc[2], 1); doFMA(wc[3], 2);
        int d = 3;
        #pragma unroll 1
        for (int j = 1; j < IND / 4; ++j) {            // chunks 1..15
            wc = wn;
            if (j + 1 < IND / 4)
                wn = *(const f32x4*)(w1row + 4 * (j + 1));  // prefetch next
            doFMA(wc[0], d); doFMA(wc[1], d + 1);
            doFMA(wc[2], d + 2); doFMA(wc[3], d + 3);
            d += 4;
        }
        #pragma unroll
        for (int r = 0; r < RPB; ++r) hpL[r * HD + n] = acc[r];
    }
    __syncthreads();                                   // B2 (hpL ready)

    // per-lane C-init byte offset into bias table: feature nt*16+q*4
    const int bIoff = q * 16;                          // + nt*64 at use site

    if (w == 0) {
        // ================= PRODUCER: layer 1 + layer 2 =================
        __builtin_amdgcn_s_setprio(0);
        float w1x[32];
        #pragma unroll
        for (int kk = 0; kk < 4; ++kk)
            #pragma unroll
            for (int j = 0; j < 8; ++j)
                w1x[kk * 8 + j] = W1[(kk * 32 + q * 8 + j) * IND];

        short8 W2A[8][4];
        #pragma unroll
        for (int nt = 0; nt < 8; ++nt) {
            #pragma unroll
            for (int kk = 0; kk < 4; ++kk) {
                const float* p2 = W2 + (nt * 16 + lm) * HD + kk * 32 + q * 8;
                f32x4 v0 = *(const f32x4*)(p2);        // aligned (32B offset)
                f32x4 v1 = *(const f32x4*)(p2 + 4);
                S8U a2;
                a2.u[0] = pk_bf16(v0[0], v0[1]);
                a2.u[1] = pk_bf16(v0[2], v0[3]);
                a2.u[2] = pk_bf16(v1[0], v1[1]);
                a2.u[3] = pk_bf16(v1[2], v1[3]);
                W2A[nt][kk] = a2.s8;
            }
        }
        int wrOff[8];
        #pragma unroll
        for (int nt = 0; nt < 8; ++nt)
            wrOff[nt] = lm * 256 + (((2 * nt + (q >> 1)) ^ swz) << 4) + ((q & 1) << 3);
        const char* b2c = (const char*)b2f;

        #pragma unroll 1
        for (int tt = 0; tt < TPB; ++tt) {
            // ---- layer 1: build Y1 fragment for this tile ----
            const int s    = tt * 16 + lm;             // 0..815
            const unsigned row = (unsigned)s / KQ;     // 0..15
            const int k    = s - (int)row * KQ;
            const float x0 = xL[row];
            const float X  = fmaf((xmax - x0) * 0.5f, sSteps[k] + 1.0f, x0);
            short8 Y1[4];
            #pragma unroll
            for (int kk = 0; kk < 4; ++kk) {
                const float* hp = hpL + row * HD + kk * 32 + q * 8;
                f32x4 ha = *(const f32x4*)hp;
                f32x4 hb = *(const f32x4*)(hp + 4);
                S8U u;
                u.u[0] = pk_bf16(fmaxf(fmaf(X, w1x[kk*8+0], ha[0]), 0.f),
                                 fmaxf(fmaf(X, w1x[kk*8+1], ha[1]), 0.f));
                u.u[1] = pk_bf16(fmaxf(fmaf(X, w1x[kk*8+2], ha[2]), 0.f),
                                 fmaxf(fmaf(X, w1x[kk*8+3], ha[3]), 0.f));
                u.u[2] = pk_bf16(fmaxf(fmaf(X, w1x[kk*8+4], hb[0]), 0.f),
                                 fmaxf(fmaf(X, w1x[kk*8+5], hb[1]), 0.f));
                u.u[3] = pk_bf16(fmaxf(fmaf(X, w1x[kk*8+6], hb[2]), 0.f),
                                 fmaxf(fmaf(X, w1x[kk*8+7], hb[3]), 0.f));
                Y1[kk] = u.s8;
            }

            // ---- layer 2: C init from LDS bias table, 32 MFMA ----
            f32x4 C[8];
            #pragma unroll
            for (int nt = 0; nt < 8; ++nt)
                C[nt] = *(const f32x4*)(b2c + nt * 64 + bIoff);
            #pragma unroll
            for (int kk = 0; kk < 4; ++kk)
                #pragma unroll
                for (int nt = 0; nt < 8; ++nt)
                    C[nt] = __builtin_amdgcn_mfma_f32_16x16x32_bf16(W2A[nt][kk], Y1[kk], C[nt], 0, 0, 0);

            // ---- relu + pack + write Y2 ----
            char* d2 = y2x[tt & 1];
            #pragma unroll
            for (int nt = 0; nt < 8; ++nt) {
                unsigned lo = pk_bf16(fmaxf(C[nt][0], 0.f), fmaxf(C[nt][1], 0.f));
                unsigned hi = pk_bf16(fmaxf(C[nt][2], 0.f), fmaxf(C[nt][3], 0.f));
                *(int2*)(d2 + wrOff[nt]) = make_int2((int)lo, (int)hi);
            }
            __syncthreads();                           // tile tt ready
        }
    } else {
        // ================= CONSUMER: layer 3 + layer 4 =================
        __builtin_amdgcn_s_setprio(1);                 // consumer is critical
        short8 W3A[8][4];
        f32x4  W4c[8];
        #pragma unroll
        for (int nt = 0; nt < 8; ++nt) {
            #pragma unroll
            for (int kk = 0; kk < 4; ++kk) {
                const float* p3 = W3 + (nt * 16 + lm) * HD + kk * 32 + q * 8;
                f32x4 v0 = *(const f32x4*)(p3);        // aligned (32B offset)
                f32x4 v1 = *(const f32x4*)(p3 + 4);
                S8U a3;
                a3.u[0] = pk_bf16(v0[0], v0[1]);
                a3.u[1] = pk_bf16(v0[2], v0[3]);
                a3.u[2] = pk_bf16(v1[0], v1[1]);
                a3.u[3] = pk_bf16(v1[2], v1[3]);
                W3A[nt][kk] = a3.s8;
            }
            W4c[nt] = *(const f32x4*)(W4 + nt * 16 + q * 4);
        }
        const float b4v = b4[0];
        int rdOff[4];
        #pragma unroll
        for (int kk = 0; kk < 4; ++kk)
            rdOff[kk] = lm * 256 + (((kk * 4 + q) ^ swz) << 4);
        const char* b3c = (const char*)b3f;

        #pragma unroll 1
        for (int tt = 0; tt < TPB; ++tt) {
            __syncthreads();                           // wait for tile tt
            const char* s2 = y2x[tt & 1];

            // chain head: Y2 reads + C-init reads, all pipelined LDS
            short8 Y2[4];
            #pragma unroll
            for (int kk = 0; kk < 4; ++kk)
                Y2[kk] = *(const short8*)(s2 + rdOff[kk]);
            f32x4 C[8];
            #pragma unroll
            for (int nt = 0; nt < 8; ++nt)
                C[nt] = *(const f32x4*)(b3c + nt * 64 + bIoff);

            #pragma unroll
            for (int kk = 0; kk < 4; ++kk)
                #pragma unroll
                for (int nt = 0; nt < 8; ++nt)
                    C[nt] = __builtin_amdgcn_mfma_f32_16x16x32_bf16(W3A[nt][kk], Y2[kk], C[nt], 0, 0, 0);

            // ---- layer 4 per-lane partial: NO shuffles, straight to LDS ----
            float p = 0.f;
            #pragma unroll
            for (int nt = 0; nt < 8; ++nt) {
                p = fmaf(fmaxf(C[nt][0], 0.f), W4c[nt][0], p);
                p = fmaf(fmaxf(C[nt][1], 0.f), W4c[nt][1], p);
                p = fmaf(fmaxf(C[nt][2], 0.f), W4c[nt][2], p);
                p = fmaf(fmaxf(C[nt][3], 0.f), W4c[nt][3], p);
            }
            vs4[tt * 64 + lane] = p;                   // conflict-free
        }

        // ---- deferred epilogue: 4-way quarter sum + elu + ccw + reduce ----
        {
            const int r   = lane >> 2;                 // row 0..15
            const int sub = lane & 3;
            float a = 0.f;
            #pragma unroll 1
            for (int j = 0; j < 13; ++j) {
                int k = sub + 4 * j;
                if (k < KQ) {
                    int s   = r * KQ + k;
                    int tt  = s >> 4;
                    int lm2 = s & 15;
                    const float* vb = vs4 + tt * 64 + lm2;
                    float y4 = vb[0] + vb[16] + vb[32] + vb[48] + b4v;
                    float f  = (y4 > 0.f) ? (y4 + 1.f) : __expf(y4);
                    a = fmaf(f, sCcw[k], a);
                }
            }
            a += __shfl_xor(a, 1);
            a += __shfl_xor(a, 2);
            if (sub == 0)
                out[rowBase + r] = a * (xmax - xL[r]) * 0.5f;
        }
    }
}

// ---------------------------------------------------------------------------
extern "C" void kernel_launch(void* const* d_in, const int* in_sizes, int n_in,
                              void* d_out, int out_size, void* d_ws, size_t ws_size,
                              hipStream_t stream)
{
    const float* x  = (const float*)d_in[0];
    const float* h  = (const float*)d_in[1];
    const float* W1 = (const float*)d_in[2];
    const float* b1 = (const float*)d_in[3];
    const float* W2 = (const float*)d_in[4];
    const float* b2 = (const float*)d_in[5];
    const float* W3 = (const float*)d_in[6];
    const float* b3 = (const float*)d_in[7];
    const float* W4 = (const float*)d_in[8];
    const float* b4 = (const float*)d_in[9];
    float* out = (float*)d_out;

    umnn_fused<<<GRID, BLK, 0, stream>>>(x, h, W1, b1, W2, b2, W3, b3,
                                         W4, b4, out);
}